// Round 7
// baseline (4120.858 us; speedup 1.0000x reference)
//
#include <hip/hip_runtime.h>
#include <cstdint>
#include <cstddef>

#define SEQ 1024
#define DMODEL 768
#define NHEAD 12
#define DHEAD 64
#define NLAYER 4
#define NEXP 8
#define DHID 1536
#define VOCAB 512
#define NTOK 4096   // B*S

typedef __attribute__((ext_vector_type(4))) float f32x4;
typedef __attribute__((ext_vector_type(8))) unsigned short us8v;
typedef __attribute__((ext_vector_type(4))) unsigned short us4v;
typedef __attribute__((ext_vector_type(8))) __bf16 bf16x8;
union FragU { us8v u; bf16x8 b; };
typedef unsigned short u16;

// ---- split helpers: hi = truncated top16, lo = top16 of (x - hi). Exact same
// math everywhere (producers + weight pre-split) so numerics are bit-identical
// to the round-6 in-GEMM cvt8 path.
__device__ __forceinline__ void split1(float x, u16& h, u16& l) {
  unsigned int u = __float_as_uint(x);
  h = (u16)(u >> 16);
  float fl = x - __uint_as_float(u & 0xffff0000u);
  l = (u16)(__float_as_uint(fl) >> 16);
}

__device__ __forceinline__ void cvt8(const f32x4 x0, const f32x4 x1, us8v& h, us8v& l) {
#pragma unroll
  for (int j = 0; j < 4; j++) { u16 hh, ll; split1(x0[j], hh, ll); h[j] = hh; l[j] = ll; }
#pragma unroll
  for (int j = 0; j < 4; j++) { u16 hh, ll; split1(x1[j], hh, ll); h[4 + j] = hh; l[4 + j] = ll; }
}

__device__ __forceinline__ void cvt4(float a, float b, float c, float d, us4v& h, us4v& l) {
  float x[4] = {a, b, c, d};
#pragma unroll
  for (int j = 0; j < 4; j++) { u16 hh, ll; split1(x[j], hh, ll); h[j] = hh; l[j] = ll; }
}

// ---------------- embed ----------------
__global__ __launch_bounds__(256) void embed_kernel(const int* __restrict__ x,
    const float* __restrict__ tok, const float* __restrict__ pos, float* __restrict__ h) {
  int i = blockIdx.x * 256 + threadIdx.x;  // over NTOK*DMODEL
  int n = i / DMODEL, d = i - n * DMODEL;
  int s = n & (SEQ - 1);
  h[i] = tok[(size_t)x[n] * DMODEL + d] + pos[(size_t)s * DMODEL + d];
}

// ---------------- layernorm: fp32 out + hi/lo bf16 planes ----------------
__global__ __launch_bounds__(256) void ln_kernel(const float* __restrict__ x,
    const float* __restrict__ g, const float* __restrict__ b, float* __restrict__ y,
    u16* __restrict__ yh, u16* __restrict__ yl) {
  int row = blockIdx.x;
  const float* xr = x + (size_t)row * DMODEL;
  int t = threadIdx.x;
  float v0 = xr[t], v1 = xr[t + 256], v2 = xr[t + 512];
  float s = v0 + v1 + v2;
  float s2 = v0 * v0 + v1 * v1 + v2 * v2;
  for (int off = 32; off; off >>= 1) { s += __shfl_down(s, off); s2 += __shfl_down(s2, off); }
  __shared__ float rs[4], rq[4];
  if ((t & 63) == 0) { rs[t >> 6] = s; rq[t >> 6] = s2; }
  __syncthreads();
  float S  = rs[0] + rs[1] + rs[2] + rs[3];
  float S2 = rq[0] + rq[1] + rq[2] + rq[3];
  float m = S * (1.f / DMODEL);
  float var = S2 * (1.f / DMODEL) - m * m;
  float r = rsqrtf(var + 1e-5f);
  size_t base = (size_t)row * DMODEL;
#pragma unroll
  for (int q = 0; q < 3; q++) {
    int idx = t + q * 256;
    float v = (q == 0 ? v0 : (q == 1 ? v1 : v2));
    float o = (v - m) * r * g[idx] + b[idx];
    y[base + idx] = o;
    u16 hh, ll; split1(o, hh, ll);
    yh[base + idx] = hh; yl[base + idx] = ll;
  }
}

// ---------------- weight pre-split kernels ----------------
// split_tr: src [K][N] fp32 (slab z: +z*K*N) -> dh/dl [N][K] bf16 planes.
// 64x64 tile through LDS so both global read and write are coalesced.
__global__ __launch_bounds__(256) void split_tr_kernel(const float* __restrict__ src,
    u16* __restrict__ dh, u16* __restrict__ dl, int K, int N) {
  size_t slab = (size_t)blockIdx.z * K * N;
  src += slab; dh += slab; dl += slab;
  int n0 = blockIdx.x * 64, k0 = blockIdx.y * 64;
  __shared__ u16 Th[64][72], Tl[64][72];   // [n][k]
  int t = threadIdx.x;
  int vk = (t >> 4) * 4;
  int vn = (t & 15) * 4;
  const float* sp = src + (size_t)(k0 + vk) * N + n0 + vn;
  f32x4 r0 = *(const f32x4*)(sp);
  f32x4 r1 = *(const f32x4*)(sp + N);
  f32x4 r2 = *(const f32x4*)(sp + 2 * N);
  f32x4 r3 = *(const f32x4*)(sp + 3 * N);
#pragma unroll
  for (int j = 0; j < 4; j++) {
    us4v hh, ll;
    cvt4(r0[j], r1[j], r2[j], r3[j], hh, ll);
    *(us4v*)&Th[vn + j][vk] = hh;
    *(us4v*)&Tl[vn + j][vk] = ll;
  }
  __syncthreads();
  int nr = t >> 2, kc = (t & 3) * 16;
  u16* dhp = dh + (size_t)(n0 + nr) * K + k0 + kc;
  u16* dlp = dl + (size_t)(n0 + nr) * K + k0 + kc;
  *(us8v*)dhp       = *(const us8v*)&Th[nr][kc];
  *(us8v*)(dhp + 8) = *(const us8v*)&Th[nr][kc + 8];
  *(us8v*)dlp       = *(const us8v*)&Tl[nr][kc];
  *(us8v*)(dlp + 8) = *(const us8v*)&Tl[nr][kc + 8];
}

// split_copy: src already [N][K]-contiguous (lm head tok_emb [V][D])
__global__ __launch_bounds__(256) void split_copy_kernel(const float* __restrict__ src,
    u16* __restrict__ dh, u16* __restrict__ dl) {
  int i = (blockIdx.x * 256 + threadIdx.x) * 8;
  f32x4 x0 = *(const f32x4*)(src + i);
  f32x4 x1 = *(const f32x4*)(src + i + 4);
  us8v h, l; cvt8(x0, x1, h, l);
  *(us8v*)&dh[i] = h; *(us8v*)&dl[i] = l;
}

// ---------------- split-bf16 MFMA GEMM (pre-split inputs) ----------------
// 128x128 tile, 4 waves (2x2), 4x4 16x16 frags/wave, K-step 32.
// A: [M][K] hi/lo planes; B: [N][K] hi/lo planes (pre-transposed weights).
// Staging is now a pure vectorized copy: zero VALU, zero scalar gathers.
#define BM 128
#define BN 128
#define BK 32

__device__ __forceinline__ int chx(int row, int kb) {
  return row * 32 + ((kb ^ ((row >> 1) & 3)) << 3);   // ushort units, 16B chunks
}

template<bool RESID>
__global__ __launch_bounds__(256, 2) void gemm_mfma_s(
    const u16* __restrict__ Ah, const u16* __restrict__ Al,
    const u16* __restrict__ Bh, const u16* __restrict__ Bl,
    const float* __restrict__ bias, float* __restrict__ C,
    int Nn, int K)
{
  __shared__ __align__(16) u16 AsH[BM * 32], AsL[BM * 32];
  __shared__ __align__(16) u16 BsH[BN * 32], BsL[BN * 32];
  int bm = blockIdx.y * BM, bn = blockIdx.x * BN;
  int tid = threadIdx.x;
  int lane = tid & 63;
  int wid = tid >> 6;
  int wr = wid >> 1, wc = wid & 1;
  int frow = lane & 15, fkb = lane >> 4;
  f32x4 zero = {0.f, 0.f, 0.f, 0.f};
  f32x4 acc[4][4];
#pragma unroll
  for (int i = 0; i < 4; i++)
#pragma unroll
    for (int j = 0; j < 4; j++) acc[i][j] = zero;

  int sr = tid & 127;
  bool doB = tid >= 128;

  for (int k0 = 0; k0 < K; k0 += BK) {
    if (!doB) {
      const u16* ph = Ah + (size_t)(bm + sr) * K + k0;
      const u16* pl = Al + (size_t)(bm + sr) * K + k0;
#pragma unroll
      for (int c = 0; c < 4; c++) {
        *(us8v*)&AsH[chx(sr, c)] = *(const us8v*)(ph + c * 8);
        *(us8v*)&AsL[chx(sr, c)] = *(const us8v*)(pl + c * 8);
      }
    } else {
      const u16* ph = Bh + (size_t)(bn + sr) * K + k0;
      const u16* pl = Bl + (size_t)(bn + sr) * K + k0;
#pragma unroll
      for (int c = 0; c < 4; c++) {
        *(us8v*)&BsH[chx(sr, c)] = *(const us8v*)(ph + c * 8);
        *(us8v*)&BsL[chx(sr, c)] = *(const us8v*)(pl + c * 8);
      }
    }
    __syncthreads();
    FragU ah[4], al[4], bh[4], bl[4];
#pragma unroll
    for (int i = 0; i < 4; i++) {
      ah[i].u = *(const us8v*)&AsH[chx(wr * 64 + i * 16 + frow, fkb)];
      al[i].u = *(const us8v*)&AsL[chx(wr * 64 + i * 16 + frow, fkb)];
      bh[i].u = *(const us8v*)&BsH[chx(wc * 64 + i * 16 + frow, fkb)];
      bl[i].u = *(const us8v*)&BsL[chx(wc * 64 + i * 16 + frow, fkb)];
    }
#pragma unroll
    for (int i = 0; i < 4; i++)
#pragma unroll
      for (int j = 0; j < 4; j++)
        acc[i][j] = __builtin_amdgcn_mfma_f32_16x16x32_bf16(ah[i].b, bh[j].b, acc[i][j], 0, 0, 0);
#pragma unroll
    for (int i = 0; i < 4; i++)
#pragma unroll
      for (int j = 0; j < 4; j++)
        acc[i][j] = __builtin_amdgcn_mfma_f32_16x16x32_bf16(ah[i].b, bl[j].b, acc[i][j], 0, 0, 0);
#pragma unroll
    for (int i = 0; i < 4; i++)
#pragma unroll
      for (int j = 0; j < 4; j++)
        acc[i][j] = __builtin_amdgcn_mfma_f32_16x16x32_bf16(al[i].b, bh[j].b, acc[i][j], 0, 0, 0);
    __syncthreads();
  }
#pragma unroll
  for (int i = 0; i < 4; i++) {
    int rbase = bm + wr * 64 + i * 16 + (lane >> 4) * 4;
#pragma unroll
    for (int q = 0; q < 4; q++) {
      float* Crow = C + (size_t)(rbase + q) * Nn;
#pragma unroll
      for (int j = 0; j < 4; j++) {
        int col = bn + wc * 64 + j * 16 + frow;
        float v = acc[i][j][q] + (bias ? bias[col] : 0.f);
        if (RESID) v += Crow[col];
        Crow[col] = v;
      }
    }
  }
}

// ---------------- MoE gathered split GEMM (pre-split inputs) ----------------
__device__ __forceinline__ float gelu_f(float x) {
  float x3 = x * x * x;
  return 0.5f * x * (1.f + tanhf(0.7978845608028654f * (x + 0.044715f * x3)));
}

// GELU=true  (w1): A-gather row = ent>>1 (token rows), out = split H1h/H1l with gelu
// GELU=false (w2): A-gather row = ent (H1 rows),       out = fp32 eo scaled by tokw
template<bool GELU>
__global__ __launch_bounds__(256, 2) void gemm_moe_mfma_s(
    const u16* __restrict__ Ah, const u16* __restrict__ Al,
    const u16* __restrict__ Bh, const u16* __restrict__ Bl,   // [E][N][K] planes
    const float* __restrict__ biasBase,
    float* __restrict__ Cf, u16* __restrict__ Ch, u16* __restrict__ Cl,
    const int* __restrict__ entries, const int* __restrict__ counts,
    const float* __restrict__ tokw, int Nn, int K)
{
  int e = blockIdx.z;
  int cnt = counts[e];
  int bm = blockIdx.y * BM;
  if (bm >= cnt) return;
  const u16* Bph = Bh + (size_t)e * K * Nn;
  const u16* Bpl = Bl + (size_t)e * K * Nn;
  const float* bias = biasBase + (size_t)e * Nn;
  const int* list = entries + e * NTOK;
  int bn = blockIdx.x * BN;
  int tid = threadIdx.x;
  int lane = tid & 63;
  int wid = tid >> 6;
  int wr = wid >> 1, wc = wid & 1;
  int frow = lane & 15, fkb = lane >> 4;

  __shared__ __align__(16) u16 AsH[BM * 32], AsL[BM * 32];
  __shared__ __align__(16) u16 BsH[BN * 32], BsL[BN * 32];
  __shared__ int rowent[BM];
  if (tid < BM) {
    int gr = bm + tid;
    rowent[tid] = (gr < cnt) ? list[gr] : -1;
  }
  __syncthreads();

  f32x4 zero = {0.f, 0.f, 0.f, 0.f};
  f32x4 acc[4][4];
#pragma unroll
  for (int i = 0; i < 4; i++)
#pragma unroll
    for (int j = 0; j < 4; j++) acc[i][j] = zero;

  int sr = tid & 127;
  bool doB = tid >= 128;

  for (int k0 = 0; k0 < K; k0 += BK) {
    if (!doB) {
      int ent = rowent[sr];
      if (ent >= 0) {
        int arow = GELU ? (ent >> 1) : ent;
        const u16* ph = Ah + (size_t)arow * K + k0;
        const u16* pl = Al + (size_t)arow * K + k0;
#pragma unroll
        for (int c = 0; c < 4; c++) {
          *(us8v*)&AsH[chx(sr, c)] = *(const us8v*)(ph + c * 8);
          *(us8v*)&AsL[chx(sr, c)] = *(const us8v*)(pl + c * 8);
        }
      } else {
        us8v z = {0, 0, 0, 0, 0, 0, 0, 0};
#pragma unroll
        for (int c = 0; c < 4; c++) {
          *(us8v*)&AsH[chx(sr, c)] = z;
          *(us8v*)&AsL[chx(sr, c)] = z;
        }
      }
    } else {
      const u16* ph = Bph + (size_t)(bn + sr) * K + k0;
      const u16* pl = Bpl + (size_t)(bn + sr) * K + k0;
#pragma unroll
      for (int c = 0; c < 4; c++) {
        *(us8v*)&BsH[chx(sr, c)] = *(const us8v*)(ph + c * 8);
        *(us8v*)&BsL[chx(sr, c)] = *(const us8v*)(pl + c * 8);
      }
    }
    __syncthreads();
    FragU ah[4], al[4], bh[4], bl[4];
#pragma unroll
    for (int i = 0; i < 4; i++) {
      ah[i].u = *(const us8v*)&AsH[chx(wr * 64 + i * 16 + frow, fkb)];
      al[i].u = *(const us8v*)&AsL[chx(wr * 64 + i * 16 + frow, fkb)];
      bh[i].u = *(const us8v*)&BsH[chx(wc * 64 + i * 16 + frow, fkb)];
      bl[i].u = *(const us8v*)&BsL[chx(wc * 64 + i * 16 + frow, fkb)];
    }
#pragma unroll
    for (int i = 0; i < 4; i++)
#pragma unroll
      for (int j = 0; j < 4; j++)
        acc[i][j] = __builtin_amdgcn_mfma_f32_16x16x32_bf16(ah[i].b, bh[j].b, acc[i][j], 0, 0, 0);
#pragma unroll
    for (int i = 0; i < 4; i++)
#pragma unroll
      for (int j = 0; j < 4; j++)
        acc[i][j] = __builtin_amdgcn_mfma_f32_16x16x32_bf16(ah[i].b, bl[j].b, acc[i][j], 0, 0, 0);
#pragma unroll
    for (int i = 0; i < 4; i++)
#pragma unroll
      for (int j = 0; j < 4; j++)
        acc[i][j] = __builtin_amdgcn_mfma_f32_16x16x32_bf16(al[i].b, bh[j].b, acc[i][j], 0, 0, 0);
    __syncthreads();
  }
#pragma unroll
  for (int i = 0; i < 4; i++) {
    int rloc = wr * 64 + i * 16 + (lane >> 4) * 4;
#pragma unroll
    for (int q = 0; q < 4; q++) {
      int ent = rowent[rloc + q];
      if (ent < 0) continue;
#pragma unroll
      for (int j = 0; j < 4; j++) {
        int col = bn + wc * 64 + j * 16 + frow;
        float v = acc[i][j][q] + bias[col];
        if (GELU) {
          v = gelu_f(v);
          u16 hh, ll; split1(v, hh, ll);
          Ch[(size_t)ent * Nn + col] = hh;
          Cl[(size_t)ent * Nn + col] = ll;
        } else {
          Cf[(size_t)ent * Nn + col] = v * tokw[ent];
        }
      }
    }
  }
}

// ---------------- MFMA flash attention (round-6 verified build) ----------------
// Front half MFMA (Q-in-regs, K hi/lo swizzled LDS, 3-MFMA QK^T, online softmax
// in the MFMA C-frame); back half VALU PV on fp32 P/V (the MFMA-PV variant has
// an unresolved deterministic bug — bisected rounds 3-6; do not reintroduce
// without a finer bisection). Epilogue now emits hi/lo planes for proj's A.
__device__ __forceinline__ int kvx(int row, int col) {   // ushort units; rows of 64
  return (row << 6) + (((((col >> 3) ^ (row & 7))) << 3) | (col & 7));
}

__global__ __launch_bounds__(256, 2) void fattn_mfma(const float* __restrict__ qkv,
                                                     u16* __restrict__ outh,
                                                     u16* __restrict__ outl) {
  int qt = blockIdx.x;           // q tile 0..15
  int hh = blockIdx.y;           // head
  int b  = blockIdx.z;           // batch
  int n0 = b * SEQ;
  int q0 = qt * 64;
  const float* base = qkv + (size_t)n0 * (3 * DMODEL);
  int tid = threadIdx.x;
  int lane = tid & 63;
  int w = tid >> 6;
  int fr = lane & 15, fg = lane >> 4;

  __shared__ __align__(16) u16 KsH[64 * 64], KsL[64 * 64];
  __shared__ float Vs[64][64];     // fp32 V[k][d]
  __shared__ float Psf[4][16][68]; // fp32 P[q(wave-local)][key], per wave

  FragU qh[2], ql[2];
  {
    const float* qrow = base + (size_t)(q0 + w * 16 + fr) * (3 * DMODEL) + hh * DHEAD;
#pragma unroll
    for (int s = 0; s < 2; s++) {
      f32x4 x0 = *(const f32x4*)(qrow + s * 32 + fg * 8);
      f32x4 x1 = *(const f32x4*)(qrow + s * 32 + fg * 8 + 4);
      x0 *= 0.125f; x1 *= 0.125f;
      cvt8(x0, x1, qh[s].u, ql[s].u);
    }
  }

  f32x4 O[4];
  float m_i[4], l_i[4];
#pragma unroll
  for (int c = 0; c < 4; c++) O[c] = (f32x4){0.f, 0.f, 0.f, 0.f};
#pragma unroll
  for (int r = 0; r < 4; r++) { m_i[r] = -3.4e38f; l_i[r] = 0.f; }

  int krow = tid >> 2, kd = (tid & 3) << 4;

  for (int kt = 0; kt <= qt; kt++) {
    int k0 = kt * 64;
    __syncthreads();
    {  // stage K hi/lo
      const float* kp = base + (size_t)(k0 + krow) * (3 * DMODEL) + DMODEL + hh * DHEAD + kd;
      f32x4 x0 = *(const f32x4*)(kp);
      f32x4 x1 = *(const f32x4*)(kp + 4);
      f32x4 x2 = *(const f32x4*)(kp + 8);
      f32x4 x3 = *(const f32x4*)(kp + 12);
      us8v h0, l0, h1, l1;
      cvt8(x0, x1, h0, l0); cvt8(x2, x3, h1, l1);
      *(us8v*)&KsH[kvx(krow, kd)]     = h0;
      *(us8v*)&KsH[kvx(krow, kd + 8)] = h1;
      *(us8v*)&KsL[kvx(krow, kd)]     = l0;
      *(us8v*)&KsL[kvx(krow, kd + 8)] = l1;
    }
    {  // stage V fp32
#pragma unroll
      for (int it = 0; it < 16; it++) {
        int i = tid + it * 256;
        int r = i >> 6, c = i & 63;
        Vs[r][c] = base[(size_t)(k0 + r) * (3 * DMODEL) + 2 * DMODEL + hh * DHEAD + c];
      }
    }
    __syncthreads();

    // S = (Q/8) K^T
    f32x4 sa[4];
#pragma unroll
    for (int f = 0; f < 4; f++) sa[f] = (f32x4){0.f, 0.f, 0.f, 0.f};
#pragma unroll
    for (int s = 0; s < 2; s++) {
#pragma unroll
      for (int f = 0; f < 4; f++) {
        FragU kh, kl;
        kh.u = *(const us8v*)&KsH[kvx(f * 16 + fr, s * 32 + fg * 8)];
        kl.u = *(const us8v*)&KsL[kvx(f * 16 + fr, s * 32 + fg * 8)];
        sa[f] = __builtin_amdgcn_mfma_f32_16x16x32_bf16(qh[s].b, kh.b, sa[f], 0, 0, 0);
        sa[f] = __builtin_amdgcn_mfma_f32_16x16x32_bf16(qh[s].b, kl.b, sa[f], 0, 0, 0);
        sa[f] = __builtin_amdgcn_mfma_f32_16x16x32_bf16(ql[s].b, kh.b, sa[f], 0, 0, 0);
      }
    }
    if (kt == qt) {
#pragma unroll
      for (int f = 0; f < 4; f++)
#pragma unroll
        for (int r = 0; r < 4; r++)
          if (k0 + f * 16 + fr > q0 + w * 16 + fg * 4 + r) sa[f][r] = -3.4e38f;
    }

    // online softmax; row q = fg*4+r, col key = f*16+fr
#pragma unroll
    for (int r = 0; r < 4; r++) {
      float rm = fmaxf(fmaxf(sa[0][r], sa[1][r]), fmaxf(sa[2][r], sa[3][r]));
      rm = fmaxf(rm, __shfl_xor(rm, 1));
      rm = fmaxf(rm, __shfl_xor(rm, 2));
      rm = fmaxf(rm, __shfl_xor(rm, 4));
      rm = fmaxf(rm, __shfl_xor(rm, 8));
      float mnew = fmaxf(m_i[r], rm);
      float alpha = __expf(m_i[r] - mnew);
      m_i[r] = mnew;
      float rsum = 0.f;
#pragma unroll
      for (int f = 0; f < 4; f++) {
        float p = __expf(sa[f][r] - mnew);
        rsum += p;
        Psf[w][fg * 4 + r][f * 16 + fr] = p;
      }
      rsum += __shfl_xor(rsum, 1);
      rsum += __shfl_xor(rsum, 2);
      rsum += __shfl_xor(rsum, 4);
      rsum += __shfl_xor(rsum, 8);
      l_i[r] = l_i[r] * alpha + rsum;
#pragma unroll
      for (int c = 0; c < 4; c++) O[c][r] *= alpha;
    }
    __syncthreads();   // order cross-lane P stores before PV reads

    // O += P V (VALU)
    for (int kk = 0; kk < 64; kk++) {
      float pr[4], vv[4];
#pragma unroll
      for (int r = 0; r < 4; r++) pr[r] = Psf[w][fg * 4 + r][kk];
#pragma unroll
      for (int c = 0; c < 4; c++) vv[c] = Vs[kk][c * 16 + fr];
#pragma unroll
      for (int c = 0; c < 4; c++)
#pragma unroll
        for (int r = 0; r < 4; r++) O[c][r] += pr[r] * vv[c];
    }
  }

#pragma unroll
  for (int r = 0; r < 4; r++) {
    float rinv = 1.f / l_i[r];
    size_t obase = (size_t)(n0 + q0 + w * 16 + fg * 4 + r) * DMODEL + hh * DHEAD;
#pragma unroll
    for (int c = 0; c < 4; c++) {
      float o = O[c][r] * rinv;
      u16 hh2, ll2; split1(o, hh2, ll2);
      outh[obase + c * 16 + fr] = hh2;
      outl[obase + c * 16 + fr] = ll2;
    }
  }
}

// ---------------- gate: 1 thread per token ----------------
__global__ __launch_bounds__(256) void gate_kernel(const float* __restrict__ xln,
    const float* __restrict__ gw, const float* __restrict__ gb,
    int* __restrict__ counts, int* __restrict__ entries, float* __restrict__ tokw) {
  int n = blockIdx.x * 256 + threadIdx.x;
  if (n >= NTOK) return;
  const float* xr = xln + (size_t)n * DMODEL;
  float gl[NEXP];
#pragma unroll
  for (int e = 0; e < NEXP; e++) gl[e] = gb[e];
  for (int dd = 0; dd < DMODEL; dd++) {
    float xv = xr[dd];
#pragma unroll
    for (int e = 0; e < NEXP; e++) gl[e] += xv * gw[dd * NEXP + e];
  }
  float mx = gl[0];
#pragma unroll
  for (int e = 1; e < NEXP; e++) mx = fmaxf(mx, gl[e]);
  float ex[NEXP];
#pragma unroll
  for (int e = 0; e < NEXP; e++) ex[e] = expf(gl[e] - mx);
  int i0 = 0; float v0 = ex[0];
#pragma unroll
  for (int e = 1; e < NEXP; e++) if (ex[e] > v0) { v0 = ex[e]; i0 = e; }
  int i1 = -1; float v1 = -1.f;
#pragma unroll
  for (int e = 0; e < NEXP; e++) if (e != i0 && ex[e] > v1) { v1 = ex[e]; i1 = e; }
  float wsum = v0 + v1;            // softmax denominator cancels in renorm
  float w0 = v0 / wsum, w1 = v1 / wsum;
  int p0 = atomicAdd(&counts[i0], 1);
  entries[i0 * NTOK + p0] = n * 2 + 0;
  tokw[n * 2 + 0] = w0;
  int p1 = atomicAdd(&counts[i1], 1);
  entries[i1 * NTOK + p1] = n * 2 + 1;
  tokw[n * 2 + 1] = w1;
}

__global__ void zero_counts(int* c) { if (threadIdx.x < NEXP) c[threadIdx.x] = 0; }

// ---------------- combine: h += eo[slot0] + eo[slot1] ----------------
__global__ __launch_bounds__(256) void combine_kernel(float* __restrict__ h,
                                                      const float* __restrict__ eo) {
  int i = blockIdx.x * 256 + threadIdx.x;
  int n = i / DMODEL, d = i - n * DMODEL;
  h[i] += eo[(size_t)(n * 2) * DMODEL + d] + eo[(size_t)(n * 2 + 1) * DMODEL + d];
}

extern "C" void kernel_launch(void* const* d_in, const int* in_sizes, int n_in,
                              void* d_out, int out_size, void* d_ws, size_t ws_size,
                              hipStream_t stream) {
  const int*   x       = (const int*)d_in[0];
  const float* tok_emb = (const float*)d_in[1];
  const float* pos_emb = (const float*)d_in[2];
  const float* ln1_g   = (const float*)d_in[3];
  const float* ln1_b   = (const float*)d_in[4];
  const float* qkv_w   = (const float*)d_in[5];
  const float* qkv_b   = (const float*)d_in[6];
  const float* proj_w  = (const float*)d_in[7];
  const float* proj_b  = (const float*)d_in[8];
  const float* ln2_g   = (const float*)d_in[9];
  const float* ln2_b   = (const float*)d_in[10];
  const float* gate_w  = (const float*)d_in[11];
  const float* gate_b  = (const float*)d_in[12];
  const float* w1      = (const float*)d_in[13];
  const float* b1      = (const float*)d_in[14];
  const float* w2      = (const float*)d_in[15];
  const float* b2      = (const float*)d_in[16];
  const float* lnf_g   = (const float*)d_in[17];
  const float* lnf_b   = (const float*)d_in[18];
  float* out = (float*)d_out;

  const size_t ND = (size_t)NTOK * DMODEL;            // 3,145,728
  char* W = (char*)d_ws;
  float* h      = (float*)W;  W += ND * 4;
  float* xln    = (float*)W;  W += ND * 4;
  u16*   xh     = (u16*)W;    W += ND * 2;
  u16*   xl     = (u16*)W;    W += ND * 2;
  float* qkvbuf = (float*)W;  W += 3 * ND * 4;
  u16*   aoh    = (u16*)W;    W += ND * 2;
  u16*   aol    = (u16*)W;    W += ND * 2;
  u16*   H1h    = (u16*)W;    W += (size_t)2 * NTOK * DHID * 2;
  u16*   H1l    = (u16*)W;    W += (size_t)2 * NTOK * DHID * 2;
  float* eo     = (float*)W;  W += (size_t)2 * NTOK * DMODEL * 4;
  float* tokw   = (float*)W;  W += 2 * NTOK * 4;
  int*   counts = (int*)W;    W += 32;
  int*   entries= (int*)W;    W += (size_t)NEXP * NTOK * 4;
  u16*   WTqh   = (u16*)W;    W += (size_t)DMODEL * 3 * DMODEL * 2;
  u16*   WTql   = (u16*)W;    W += (size_t)DMODEL * 3 * DMODEL * 2;
  u16*   WTph   = (u16*)W;    W += (size_t)DMODEL * DMODEL * 2;
  u16*   WTpl   = (u16*)W;    W += (size_t)DMODEL * DMODEL * 2;
  u16*   WT1h   = (u16*)W;    W += (size_t)NEXP * DMODEL * DHID * 2;
  u16*   WT1l   = (u16*)W;    W += (size_t)NEXP * DMODEL * DHID * 2;
  u16*   WT2h   = (u16*)W;    W += (size_t)NEXP * DHID * DMODEL * 2;
  u16*   WT2l   = (u16*)W;    W += (size_t)NEXP * DHID * DMODEL * 2;

  dim3 blk(256);
  embed_kernel<<<ND / 256, blk, 0, stream>>>(x, tok_emb, pos_emb, h);
  for (int l = 0; l < NLAYER; l++) {
    // pre-split+transpose this layer's weights into [N][K] hi/lo planes
    split_tr_kernel<<<dim3(3 * DMODEL / 64, DMODEL / 64, 1), blk, 0, stream>>>(
        qkv_w + (size_t)l * DMODEL * 3 * DMODEL, WTqh, WTql, DMODEL, 3 * DMODEL);
    split_tr_kernel<<<dim3(DMODEL / 64, DMODEL / 64, 1), blk, 0, stream>>>(
        proj_w + (size_t)l * DMODEL * DMODEL, WTph, WTpl, DMODEL, DMODEL);
    split_tr_kernel<<<dim3(DHID / 64, DMODEL / 64, NEXP), blk, 0, stream>>>(
        w1 + (size_t)l * NEXP * DMODEL * DHID, WT1h, WT1l, DMODEL, DHID);
    split_tr_kernel<<<dim3(DMODEL / 64, DHID / 64, NEXP), blk, 0, stream>>>(
        w2 + (size_t)l * NEXP * DHID * DMODEL, WT2h, WT2l, DHID, DMODEL);

    ln_kernel<<<NTOK, blk, 0, stream>>>(h, ln1_g + l * DMODEL, ln1_b + l * DMODEL,
                                        xln, xh, xl);
    gemm_mfma_s<false><<<dim3(3 * DMODEL / BN, NTOK / BM), blk, 0, stream>>>(
        xh, xl, WTqh, WTql, qkv_b + l * 3 * DMODEL, qkvbuf, 3 * DMODEL, DMODEL);
    fattn_mfma<<<dim3(SEQ / 64, NHEAD, 4), blk, 0, stream>>>(qkvbuf, aoh, aol);
    gemm_mfma_s<true><<<dim3(DMODEL / BN, NTOK / BM), blk, 0, stream>>>(
        aoh, aol, WTph, WTpl, proj_b + l * DMODEL, h, DMODEL, DMODEL);
    ln_kernel<<<NTOK, blk, 0, stream>>>(h, ln2_g + l * DMODEL, ln2_b + l * DMODEL,
                                        xln, xh, xl);
    zero_counts<<<1, 64, 0, stream>>>(counts);
    gate_kernel<<<NTOK / 256, blk, 0, stream>>>(
        xln, gate_w + (size_t)l * DMODEL * NEXP, gate_b + l * NEXP, counts, entries, tokw);
    gemm_moe_mfma_s<true><<<dim3(DHID / BN, NTOK / BM, NEXP), blk, 0, stream>>>(
        xh, xl, WT1h, WT1l, b1 + (size_t)l * NEXP * DHID,
        nullptr, H1h, H1l, entries, counts, tokw, DHID, DMODEL);
    gemm_moe_mfma_s<false><<<dim3(DMODEL / BN, NTOK / BM, NEXP), blk, 0, stream>>>(
        H1h, H1l, WT2h, WT2l, b2 + (size_t)l * NEXP * DMODEL,
        eo, nullptr, nullptr, entries, counts, tokw, DMODEL, DHID);
    combine_kernel<<<ND / 256, blk, 0, stream>>>(h, eo);
  }
  ln_kernel<<<NTOK, blk, 0, stream>>>(h, lnf_g, lnf_b, xln, xh, xl);
  // lm head: tok_emb is already [V][D] = [N][K]; plain split, reuse qkv region
  split_copy_kernel<<<(VOCAB * DMODEL) / (256 * 8), blk, 0, stream>>>(tok_emb, WTqh, WTql);
  gemm_mfma_s<false><<<dim3(VOCAB / BN, NTOK / BM), blk, 0, stream>>>(
      xh, xl, WTqh, WTql, nullptr, out, VOCAB, DMODEL);
}